// Round 1
// baseline (119.000 us; speedup 1.0000x reference)
//
#include <hip/hip_runtime.h>

#define VOCAB 100000
#define EMB   20
#define HID   10
#define SEQ   100
#define NLAB  15
#define BATCH 16384
#define GATES 40
#define PROW  48   // padded P row: 4 lanes x 12 slots (16B-aligned chunks)

#if __has_builtin(__builtin_amdgcn_exp2f)
__device__ __forceinline__ float exp2_f(float x){ return __builtin_amdgcn_exp2f(x); }
#else
__device__ __forceinline__ float exp2_f(float x){ float r; asm("v_exp_f32 %0, %1" : "=v"(r) : "v"(x)); return r; }
#endif
#if __has_builtin(__builtin_amdgcn_rcpf)
__device__ __forceinline__ float rcp_f(float x){ return __builtin_amdgcn_rcpf(x); }
#else
__device__ __forceinline__ float rcp_f(float x){ float r; asm("v_rcp_f32 %0, %1" : "=v"(r) : "v"(x)); return r; }
#endif

// sigmoid(x) = 1/(1+2^(-x*log2e));  tanh(x) = 1 - 2/(2^(2x*log2e)+1)
__device__ __forceinline__ float sigm_f(float x){ return rcp_f(1.f + exp2_f(-1.442695041f * x)); }
__device__ __forceinline__ float tanh_f(float x){ return fmaf(-2.f, rcp_f(1.f + exp2_f(2.885390082f * x)), 1.f); }

// broadcast lane (quadbase + K) within each 4-lane quad via DPP quad_perm
template<int CTRL>
__device__ __forceinline__ float qb(float x){
  return __int_as_float(__builtin_amdgcn_mov_dpp(__float_as_int(x), CTRL, 0xF, 0xF, true));
}

// -------- P = embed @ Wx + b, laid out [VOCAB][4 sub][4 gate][3 slot] (48/row, dummies=0)
__global__ __launch_bounds__(256)
void proj_kernel(const float* __restrict__ emb, const float* __restrict__ Wx,
                 const float* __restrict__ bias, float* __restrict__ P)
{
  int tid = blockIdx.x * 256 + threadIdx.x;
  if (tid >= VOCAB * PROW) return;
  int v    = tid / PROW;
  int slot = tid - v * PROW;
  int sb = slot / 12;
  int r  = slot - sb * 12;
  int G  = r / 3;
  int s  = r - G * 3;
  int u  = s * 4 + sb;          // hidden-unit index within gate
  float val = 0.f;
  if (u < HID) {
    int g = G * HID + u;        // Keras gate order i,f,c,o
    val = bias[g];
    #pragma unroll
    for (int k = 0; k < EMB; ++k)
      val = fmaf(emb[v * EMB + k], Wx[k * GATES + g], val);
  }
  P[tid] = val;
}

// -------- LSTM recurrence + dense head. 4 lanes per batch element.
// lane sub owns z-columns u%4==sub for ALL four gates -> cell update is lane-local.
template<bool USEP>
__global__ __launch_bounds__(256, 1)
void rnn_kernel(const int* __restrict__ x, const float* __restrict__ P,
                const float* __restrict__ Wh, const float* __restrict__ Wd,
                const float* __restrict__ bd, float* __restrict__ out,
                const float* __restrict__ emb, const float* __restrict__ Wx,
                const float* __restrict__ bias)
{
  __shared__ int   xs[64 * SEQ];
  __shared__ float Wxl[EMB * PROW];   // only used when !USEP (3.84 KB)

  const int tid = threadIdx.x;
  const int lb  = tid >> 2;     // local batch 0..63
  const int sub = tid & 3;
  const int b0  = blockIdx.x * 64;

  // stage token ids (coalesced)
  for (int i = tid; i < 64 * SEQ; i += 256) xs[i] = x[(size_t)b0 * SEQ + i];

  if constexpr (!USEP) {
    for (int i = tid; i < EMB * PROW; i += 256) {
      int k = i / PROW, slot = i - k * PROW;
      int sb2 = slot / 12, r = slot - sb2 * 12, G = r / 3, s = r - G * 3;
      int u = s * 4 + sb2;
      Wxl[i] = (u < HID) ? Wx[k * GATES + G * HID + u] : 0.f;
    }
  }

  // per-lane recurrent weights (registers, statically indexed)
  float Whr[HID][12];
  #pragma unroll
  for (int j = 0; j < 12; ++j) {
    const int G = j / 3, s = j - G * 3;
    const int u = s * 4 + sub;
    #pragma unroll
    for (int k = 0; k < HID; ++k)
      Whr[k][j] = (u < HID) ? Wh[k * GATES + G * HID + u] : 0.f;
  }
  float bb[12];
  #pragma unroll
  for (int j = 0; j < 12; ++j) {
    if constexpr (!USEP) {
      const int G = j / 3, s = j - G * 3;
      const int u = s * 4 + sub;
      bb[j] = (u < HID) ? bias[G * HID + u] : 0.f;
    } else bb[j] = 0.f;
  }

  __syncthreads();

  float h[HID], cst[3];
  #pragma unroll
  for (int k = 0; k < HID; ++k) h[k] = 0.f;
  cst[0] = cst[1] = cst[2] = 0.f;

  float4 pa, pb, pc;                // USEP prefetch regs (12 floats)
  float4 e0, e1, e2, e3, e4;        // !USEP prefetch regs (20 floats)
  {
    int row = xs[lb * SEQ];
    if constexpr (USEP) {
      const float4* q = (const float4*)(P + (size_t)row * PROW + sub * 12);
      pa = q[0]; pb = q[1]; pc = q[2];
    } else {
      const float4* q = (const float4*)(emb + (size_t)row * EMB);
      e0 = q[0]; e1 = q[1]; e2 = q[2]; e3 = q[3]; e4 = q[4];
    }
  }

  for (int t = 0; t < SEQ; ++t) {
    float z[12];
    if constexpr (USEP) {
      z[0]=pa.x; z[1]=pa.y; z[2]=pa.z; z[3]=pa.w;
      z[4]=pb.x; z[5]=pb.y; z[6]=pb.z; z[7]=pb.w;
      z[8]=pc.x; z[9]=pc.y; z[10]=pc.z; z[11]=pc.w;
    } else {
      float e[EMB];
      e[0]=e0.x; e[1]=e0.y; e[2]=e0.z; e[3]=e0.w;
      e[4]=e1.x; e[5]=e1.y; e[6]=e1.z; e[7]=e1.w;
      e[8]=e2.x; e[9]=e2.y; e[10]=e2.z; e[11]=e2.w;
      e[12]=e3.x; e[13]=e3.y; e[14]=e3.z; e[15]=e3.w;
      e[16]=e4.x; e[17]=e4.y; e[18]=e4.z; e[19]=e4.w;
      #pragma unroll
      for (int j = 0; j < 12; ++j) z[j] = bb[j];
      const int wbase = sub * 12;
      #pragma unroll
      for (int k = 0; k < EMB; ++k)
        #pragma unroll
        for (int j = 0; j < 12; ++j)
          z[j] = fmaf(e[k], Wxl[k * PROW + wbase + j], z[j]);
    }

    // prefetch next step's row while we compute
    if (t + 1 < SEQ) {
      int row = xs[lb * SEQ + t + 1];
      if constexpr (USEP) {
        const float4* q = (const float4*)(P + (size_t)row * PROW + sub * 12);
        pa = q[0]; pb = q[1]; pc = q[2];
      } else {
        const float4* q = (const float4*)(emb + (size_t)row * EMB);
        e0 = q[0]; e1 = q[1]; e2 = q[2]; e3 = q[3]; e4 = q[4];
      }
    }

    // z += h @ Wh   (pure register FMAs)
    #pragma unroll
    for (int k = 0; k < HID; ++k)
      #pragma unroll
      for (int j = 0; j < 12; ++j)
        z[j] = fmaf(h[k], Whr[k][j], z[j]);

    // activations: slots [0..2]=i, [3..5]=f, [6..8]=c(tanh), [9..11]=o
    float a[12];
    #pragma unroll
    for (int j = 0; j < 12; ++j)
      a[j] = (j / 3 == 2) ? tanh_f(z[j]) : sigm_f(z[j]);

    // lane-local cell update for owned hidden units u = s*4+sub
    float hl[3];
    #pragma unroll
    for (int s = 0; s < 3; ++s) {
      cst[s] = fmaf(a[3 + s], cst[s], a[s] * a[6 + s]);  // c = f*c + i*g
      hl[s]  = a[9 + s] * tanh_f(cst[s]);                // h = o*tanh(c)
    }

    // broadcast the 10 h values to all 4 lanes of the quad (DPP, no LDS)
    h[0] = qb<0x00>(hl[0]); h[1] = qb<0x55>(hl[0]); h[2] = qb<0xAA>(hl[0]); h[3] = qb<0xFF>(hl[0]);
    h[4] = qb<0x00>(hl[1]); h[5] = qb<0x55>(hl[1]); h[6] = qb<0xAA>(hl[1]); h[7] = qb<0xFF>(hl[1]);
    h[8] = qb<0x00>(hl[2]); h[9] = qb<0x55>(hl[2]);
  }

  // dense head: logits = h @ Wd + bd ; lane sub does j = sub, sub+4, sub+8, sub+12
  #pragma unroll
  for (int s = 0; s < 4; ++s) {
    int j = s * 4 + sub;
    if (j < NLAB) {
      float acc = bd[j];
      #pragma unroll
      for (int k = 0; k < HID; ++k)
        acc = fmaf(h[k], Wd[k * NLAB + j], acc);
      out[(size_t)(b0 + lb) * NLAB + j] = acc;
    }
  }
}

extern "C" void kernel_launch(void* const* d_in, const int* in_sizes, int n_in,
                              void* d_out, int out_size, void* d_ws, size_t ws_size,
                              hipStream_t stream) {
  (void)in_sizes; (void)n_in; (void)out_size;
  const int*   x    = (const int*)  d_in[0];
  const float* emb  = (const float*)d_in[1];
  const float* Wx   = (const float*)d_in[2];
  const float* Wh   = (const float*)d_in[3];
  const float* bias = (const float*)d_in[4];
  const float* Wd   = (const float*)d_in[5];
  const float* bd   = (const float*)d_in[6];
  float* out = (float*)d_out;

  const size_t pbytes = (size_t)VOCAB * PROW * sizeof(float);
  if (ws_size >= pbytes) {
    float* P = (float*)d_ws;
    hipLaunchKernelGGL(proj_kernel, dim3((VOCAB * PROW + 255) / 256), dim3(256), 0, stream,
                       emb, Wx, bias, P);
    hipLaunchKernelGGL((rnn_kernel<true>), dim3(BATCH / 64), dim3(256), 0, stream,
                       x, P, Wh, Wd, bd, out, emb, Wx, bias);
  } else {
    hipLaunchKernelGGL((rnn_kernel<false>), dim3(BATCH / 64), dim3(256), 0, stream,
                       x, (const float*)nullptr, Wh, Wd, bd, out, emb, Wx, bias);
  }
}

// Round 2
// 90.529 us; speedup vs baseline: 1.3145x; 1.3145x over previous
//
#include <hip/hip_runtime.h>

#define VOCAB 100000
#define EMB   20
#define HID   10
#define SEQ   100
#define NLAB  15
#define BATCH 16384
#define GATES 40
#define PROW  48   // padded P row: 4 lanes x 12 slots (16B-aligned chunks)

__device__ __forceinline__ float exp2_f(float x){ float r; asm("v_exp_f32 %0, %1" : "=v"(r) : "v"(x)); return r; }
__device__ __forceinline__ float rcp_f(float x){ float r; asm("v_rcp_f32 %0, %1" : "=v"(r) : "v"(x)); return r; }

// Gate scales folded into weights: sigmoid(x)=rcp(1+exp2(-log2e*x)),
// tanh(x)=2*rcp(1+exp2(-2*log2e*x))-1.  Column scale: c-gate gets -2log2e, others -log2e.
__device__ __host__ __forceinline__ constexpr float gscale(int G){
  return (G == 2) ? -2.885390081777927f : -1.442695040888963f;
}

// broadcast lane (quadbase + K) within each 4-lane quad via DPP quad_perm
template<int CTRL>
__device__ __forceinline__ float qb(float x){
  return __int_as_float(__builtin_amdgcn_mov_dpp(__float_as_int(x), CTRL, 0xF, 0xF, true));
}

// -------- P = (embed @ Wx + b) * gate_scale, laid out [VOCAB][4 sub][4 gate][3 slot]
// one thread per (v, sub): emb row loaded once, 12 outputs.
__global__ __launch_bounds__(256)
void proj_kernel(const float* __restrict__ emb, const float* __restrict__ Wx,
                 const float* __restrict__ bias, float* __restrict__ P)
{
  __shared__ float Wxl[EMB * PROW];
  __shared__ float bl[PROW];
  const int tid = threadIdx.x;
  for (int i = tid; i < EMB * PROW; i += 256) {
    int k = i / PROW, slot = i - k * PROW;
    int sb = slot / 12, r = slot - sb * 12, G = r / 3, s = r - G * 3, u = s * 4 + sb;
    Wxl[i] = (u < HID) ? Wx[k * GATES + G * HID + u] * gscale(G) : 0.f;
  }
  if (tid < PROW) {
    int slot = tid, sb = slot / 12, r = slot - sb * 12, G = r / 3, s = r - G * 3, u = s * 4 + sb;
    bl[slot] = (u < HID) ? bias[G * HID + u] * gscale(G) : 0.f;
  }
  __syncthreads();

  const int v   = blockIdx.x * 64 + (tid >> 2);
  const int sub = tid & 3;
  if (v >= VOCAB) return;

  const float4* er = (const float4*)(emb + (size_t)v * EMB);
  float4 e0 = er[0], e1 = er[1], e2 = er[2], e3 = er[3], e4 = er[4];
  float e[EMB] = {e0.x,e0.y,e0.z,e0.w, e1.x,e1.y,e1.z,e1.w, e2.x,e2.y,e2.z,e2.w,
                  e3.x,e3.y,e3.z,e3.w, e4.x,e4.y,e4.z,e4.w};
  const int wb = sub * 12;
  float acc[12];
  #pragma unroll
  for (int j = 0; j < 12; ++j) acc[j] = bl[wb + j];
  #pragma unroll
  for (int k = 0; k < EMB; ++k)
    #pragma unroll
    for (int j = 0; j < 12; ++j)
      acc[j] = fmaf(e[k], Wxl[k * PROW + wb + j], acc[j]);

  float4* o = (float4*)(P + (size_t)v * PROW + wb);
  o[0] = make_float4(acc[0], acc[1], acc[2],  acc[3]);
  o[1] = make_float4(acc[4], acc[5], acc[6],  acc[7]);
  o[2] = make_float4(acc[8], acc[9], acc[10], acc[11]);
}

// -------- LSTM recurrence + dense head. 4 lanes per batch element.
template<bool USEP>
__global__ __launch_bounds__(256, 1)
void rnn_kernel(const int* __restrict__ x, const float* __restrict__ P,
                const float* __restrict__ Wh, const float* __restrict__ Wd,
                const float* __restrict__ bd, float* __restrict__ out,
                const float* __restrict__ emb, const float* __restrict__ Wx,
                const float* __restrict__ bias)
{
  __shared__ int   xs[64 * SEQ];
  __shared__ float Wxl[EMB * PROW];   // !USEP only
  __shared__ float bls[PROW];         // !USEP only

  const int tid = threadIdx.x;
  const int lb  = tid >> 2;
  const int sub = tid & 3;
  const int b0  = blockIdx.x * 64;

  for (int i = tid; i < 64 * SEQ; i += 256) xs[i] = x[(size_t)b0 * SEQ + i];

  if constexpr (!USEP) {
    for (int i = tid; i < EMB * PROW; i += 256) {
      int k = i / PROW, slot = i - k * PROW;
      int sb2 = slot / 12, r = slot - sb2 * 12, G = r / 3, s = r - G * 3, u = s * 4 + sb2;
      Wxl[i] = (u < HID) ? Wx[k * GATES + G * HID + u] * gscale(G) : 0.f;
    }
    if (tid < PROW) {
      int slot = tid, sb2 = slot / 12, r = slot - sb2 * 12, G = r / 3, s = r - G * 3, u = s * 4 + sb2;
      bls[slot] = (u < HID) ? bias[G * HID + u] * gscale(G) : 0.f;
    }
  }

  // recurrent weights in registers, gate-scaled; keep-alive so the compiler
  // cannot rematerialize them as per-step global reloads (round-1: VGPR=84 < 120).
  float Whr[HID][12];
  #pragma unroll
  for (int j = 0; j < 12; ++j) {
    const int G = j / 3, s = j - G * 3, u = s * 4 + sub;
    #pragma unroll
    for (int k = 0; k < HID; ++k)
      Whr[k][j] = (u < HID) ? Wh[k * GATES + G * HID + u] * gscale(G) : 0.f;
  }
  #pragma unroll
  for (int k = 0; k < HID; ++k)
    #pragma unroll
    for (int j = 0; j < 12; ++j)
      asm volatile("" : "+v"(Whr[k][j]));

  __syncthreads();

  float h[HID], cst[3];
  #pragma unroll
  for (int k = 0; k < HID; ++k) h[k] = 0.f;
  cst[0] = cst[1] = cst[2] = 0.f;

  if constexpr (USEP) {
    float zA[12], zB[12];
    int nr;
    {
      int r0 = xs[lb * SEQ + 0], r1 = xs[lb * SEQ + 1];
      const float4* q0 = (const float4*)(P + (size_t)r0 * PROW + sub * 12);
      *(float4*)&zA[0] = q0[0]; *(float4*)&zA[4] = q0[1]; *(float4*)&zA[8] = q0[2];
      const float4* q1 = (const float4*)(P + (size_t)r1 * PROW + sub * 12);
      *(float4*)&zB[0] = q1[0]; *(float4*)&zB[4] = q1[1]; *(float4*)&zB[8] = q1[2];
      nr = xs[lb * SEQ + 2];
    }

    auto lstm_step = [&](float (&z)[12], int t) {
      // z += h @ Wh (pure register FMAs)
      #pragma unroll
      for (int k = 0; k < HID; ++k)
        #pragma unroll
        for (int j = 0; j < 12; ++j)
          z[j] = fmaf(h[k], Whr[k][j], z[j]);

      // activations (scales pre-folded): i,f,o -> r ; c -> 2r-1
      float a[12];
      #pragma unroll
      for (int j = 0; j < 12; ++j) {
        float r = rcp_f(1.f + exp2_f(z[j]));
        a[j] = (j / 3 == 2) ? fmaf(2.f, r, -1.f) : r;
      }

      // z is dead: reload it in place with row t+2 (depth-2 prefetch)
      if (t + 2 < SEQ) {
        const float4* q = (const float4*)(P + (size_t)nr * PROW + sub * 12);
        *(float4*)&z[0] = q[0]; *(float4*)&z[4] = q[1]; *(float4*)&z[8] = q[2];
        nr = xs[lb * SEQ + (t + 3 < SEQ ? t + 3 : 0)];
      }

      // lane-local cell update
      float hl[3];
      #pragma unroll
      for (int s = 0; s < 3; ++s) {
        cst[s] = fmaf(a[3 + s], cst[s], a[s] * a[6 + s]);      // c = f*c + i*g
        float r = rcp_f(1.f + exp2_f(-2.885390081777927f * cst[s]));
        hl[s] = fmaf(a[9 + s], r + r, -a[9 + s]);              // h = o*(2r-1)
      }

      h[0] = qb<0x00>(hl[0]); h[1] = qb<0x55>(hl[0]); h[2] = qb<0xAA>(hl[0]); h[3] = qb<0xFF>(hl[0]);
      h[4] = qb<0x00>(hl[1]); h[5] = qb<0x55>(hl[1]); h[6] = qb<0xAA>(hl[1]); h[7] = qb<0xFF>(hl[1]);
      h[8] = qb<0x00>(hl[2]); h[9] = qb<0x55>(hl[2]);
    };

    #pragma unroll 1
    for (int t = 0; t < SEQ; t += 2) {
      lstm_step(zA, t);
      lstm_step(zB, t + 1);
    }
  } else {
    // fallback: compute e@Wx on the fly (only if ws too small for P)
    float bb[12];
    #pragma unroll
    for (int j = 0; j < 12; ++j) bb[j] = bls[sub * 12 + j];
    float4 e0, e1, e2, e3, e4;
    {
      int row = xs[lb * SEQ];
      const float4* q = (const float4*)(emb + (size_t)row * EMB);
      e0 = q[0]; e1 = q[1]; e2 = q[2]; e3 = q[3]; e4 = q[4];
    }
    #pragma unroll 1
    for (int t = 0; t < SEQ; ++t) {
      float e[EMB] = {e0.x,e0.y,e0.z,e0.w, e1.x,e1.y,e1.z,e1.w, e2.x,e2.y,e2.z,e2.w,
                      e3.x,e3.y,e3.z,e3.w, e4.x,e4.y,e4.z,e4.w};
      float z[12];
      #pragma unroll
      for (int j = 0; j < 12; ++j) z[j] = bb[j];
      const int wbase = sub * 12;
      #pragma unroll
      for (int k = 0; k < EMB; ++k)
        #pragma unroll
        for (int j = 0; j < 12; ++j)
          z[j] = fmaf(e[k], Wxl[k * PROW + wbase + j], z[j]);
      if (t + 1 < SEQ) {
        int row = xs[lb * SEQ + t + 1];
        const float4* q = (const float4*)(emb + (size_t)row * EMB);
        e0 = q[0]; e1 = q[1]; e2 = q[2]; e3 = q[3]; e4 = q[4];
      }
      #pragma unroll
      for (int k = 0; k < HID; ++k)
        #pragma unroll
        for (int j = 0; j < 12; ++j)
          z[j] = fmaf(h[k], Whr[k][j], z[j]);
      float a[12];
      #pragma unroll
      for (int j = 0; j < 12; ++j) {
        float r = rcp_f(1.f + exp2_f(z[j]));
        a[j] = (j / 3 == 2) ? fmaf(2.f, r, -1.f) : r;
      }
      float hl[3];
      #pragma unroll
      for (int s = 0; s < 3; ++s) {
        cst[s] = fmaf(a[3 + s], cst[s], a[s] * a[6 + s]);
        float r = rcp_f(1.f + exp2_f(-2.885390081777927f * cst[s]));
        hl[s] = fmaf(a[9 + s], r + r, -a[9 + s]);
      }
      h[0] = qb<0x00>(hl[0]); h[1] = qb<0x55>(hl[0]); h[2] = qb<0xAA>(hl[0]); h[3] = qb<0xFF>(hl[0]);
      h[4] = qb<0x00>(hl[1]); h[5] = qb<0x55>(hl[1]); h[6] = qb<0xAA>(hl[1]); h[7] = qb<0xFF>(hl[1]);
      h[8] = qb<0x00>(hl[2]); h[9] = qb<0x55>(hl[2]);
    }
  }

  // dense head
  #pragma unroll
  for (int s = 0; s < 4; ++s) {
    int j = s * 4 + sub;
    if (j < NLAB) {
      float acc = bd[j];
      #pragma unroll
      for (int k = 0; k < HID; ++k)
        acc = fmaf(h[k], Wd[k * NLAB + j], acc);
      out[(size_t)(b0 + lb) * NLAB + j] = acc;
    }
  }
}

extern "C" void kernel_launch(void* const* d_in, const int* in_sizes, int n_in,
                              void* d_out, int out_size, void* d_ws, size_t ws_size,
                              hipStream_t stream) {
  (void)in_sizes; (void)n_in; (void)out_size;
  const int*   x    = (const int*)  d_in[0];
  const float* emb  = (const float*)d_in[1];
  const float* Wx   = (const float*)d_in[2];
  const float* Wh   = (const float*)d_in[3];
  const float* bias = (const float*)d_in[4];
  const float* Wd   = (const float*)d_in[5];
  const float* bd   = (const float*)d_in[6];
  float* out = (float*)d_out;

  const size_t pbytes = (size_t)VOCAB * PROW * sizeof(float);
  if (ws_size >= pbytes) {
    float* P = (float*)d_ws;
    hipLaunchKernelGGL(proj_kernel, dim3((VOCAB + 63) / 64), dim3(256), 0, stream,
                       emb, Wx, bias, P);
    hipLaunchKernelGGL((rnn_kernel<true>), dim3(BATCH / 64), dim3(256), 0, stream,
                       x, P, Wh, Wd, bd, out, emb, Wx, bias);
  } else {
    hipLaunchKernelGGL((rnn_kernel<false>), dim3(BATCH / 64), dim3(256), 0, stream,
                       x, (const float*)nullptr, Wh, Wd, bd, out, emb, Wx, bias);
  }
}

// Round 3
// 66.505 us; speedup vs baseline: 1.7893x; 1.3612x over previous
//
#include <hip/hip_runtime.h>
#include <hip/hip_fp16.h>

#define VOCAB 100000
#define EMB   20
#define HID   10
#define SEQ   100
#define NLAB  15
#define BATCH 16384
#define GATES 40
#define PROWH 48   // P row: 48 halfs = 96 B; lane sub reads halfs [sub*12 .. sub*12+11]

__device__ __forceinline__ float exp2_f(float x){ float r; asm("v_exp_f32 %0, %1" : "=v"(r) : "v"(x)); return r; }
__device__ __forceinline__ float rcp_f(float x){ float r; asm("v_rcp_f32 %0, %1" : "=v"(r) : "v"(x)); return r; }

// Gate scales folded into P/Wh/bias: sigmoid(x)=rcp(1+exp2(-log2e*x)),
// tanh(x)=2*rcp(1+exp2(-2*log2e*x))-1.  c-gate gets -2log2e, others -log2e.
__device__ __host__ __forceinline__ constexpr float gscale(int G){
  return (G == 2) ? -2.885390081777927f : -1.442695040888963f;
}

template<int CTRL>
__device__ __forceinline__ float qb(float x){
  return __int_as_float(__builtin_amdgcn_mov_dpp(__float_as_int(x), CTRL, 0xF, 0xF, true));
}

// -------- P = fp16( (embed @ Wx + b) * gate_scale ), [VOCAB][4 sub][4 gate][3 slot]
__global__ __launch_bounds__(256)
void proj_kernel(const float* __restrict__ emb, const float* __restrict__ Wx,
                 const float* __restrict__ bias, __half* __restrict__ P)
{
  __shared__ float Wxl[EMB * PROWH];
  __shared__ float bl[PROWH];
  const int tid = threadIdx.x;
  for (int i = tid; i < EMB * PROWH; i += 256) {
    int k = i / PROWH, slot = i - k * PROWH;
    int sb = slot / 12, r = slot - sb * 12, G = r / 3, s = r - G * 3, u = s * 4 + sb;
    Wxl[i] = (u < HID) ? Wx[k * GATES + G * HID + u] * gscale(G) : 0.f;
  }
  if (tid < PROWH) {
    int slot = tid, sb = slot / 12, r = slot - sb * 12, G = r / 3, s = r - G * 3, u = s * 4 + sb;
    bl[slot] = (u < HID) ? bias[G * HID + u] * gscale(G) : 0.f;
  }
  __syncthreads();

  const int v   = blockIdx.x * 64 + (tid >> 2);
  const int sub = tid & 3;
  if (v >= VOCAB) return;

  const float4* er = (const float4*)(emb + (size_t)v * EMB);
  float4 e0 = er[0], e1 = er[1], e2 = er[2], e3 = er[3], e4 = er[4];
  float e[EMB] = {e0.x,e0.y,e0.z,e0.w, e1.x,e1.y,e1.z,e1.w, e2.x,e2.y,e2.z,e2.w,
                  e3.x,e3.y,e3.z,e3.w, e4.x,e4.y,e4.z,e4.w};
  const int wb = sub * 12;
  float acc[12];
  #pragma unroll
  for (int j = 0; j < 12; ++j) acc[j] = bl[wb + j];
  #pragma unroll
  for (int k = 0; k < EMB; ++k)
    #pragma unroll
    for (int j = 0; j < 12; ++j)
      acc[j] = fmaf(e[k], Wxl[k * PROWH + wb + j], acc[j]);

  union { __half h[12]; int2 i2[3]; } u;
  #pragma unroll
  for (int j = 0; j < 12; ++j) u.h[j] = __float2half(acc[j]);
  int2* o = (int2*)(P + (size_t)v * PROWH + wb);
  o[0] = u.i2[0]; o[1] = u.i2[1]; o[2] = u.i2[2];
}

__device__ __forceinline__ void cvt12(const int2 b[3], float z[12]) {
  #pragma unroll
  for (int q = 0; q < 3; ++q) {
    float2 f0 = __half22float2(*(const __half2*)&b[q].x);
    float2 f1 = __half22float2(*(const __half2*)&b[q].y);
    z[q*4+0] = f0.x; z[q*4+1] = f0.y; z[q*4+2] = f1.x; z[q*4+3] = f1.y;
  }
}

// -------- LSTM recurrence + dense head. 4 lanes per batch element.
template<bool USEP>
__global__ __launch_bounds__(256, 1)
void rnn_kernel(const int* __restrict__ x, const __half* __restrict__ P,
                const float* __restrict__ Wh, const float* __restrict__ Wd,
                const float* __restrict__ bd, float* __restrict__ out,
                const float* __restrict__ emb, const float* __restrict__ Wx,
                const float* __restrict__ bias)
{
  __shared__ int   xs[64 * SEQ];
  __shared__ float Wxl[EMB * PROWH];   // !USEP only
  __shared__ float bls[PROWH];         // !USEP only

  const int tid = threadIdx.x;
  const int lb  = tid >> 2;
  const int sub = tid & 3;
  const int b0  = blockIdx.x * 64;

  for (int i = tid; i < 64 * SEQ; i += 256) xs[i] = x[(size_t)b0 * SEQ + i];

  if constexpr (!USEP) {
    for (int i = tid; i < EMB * PROWH; i += 256) {
      int k = i / PROWH, slot = i - k * PROWH;
      int sb2 = slot / 12, r = slot - sb2 * 12, G = r / 3, s = r - G * 3, u = s * 4 + sb2;
      Wxl[i] = (u < HID) ? Wx[k * GATES + G * HID + u] * gscale(G) : 0.f;
    }
    if (tid < PROWH) {
      int slot = tid, sb2 = slot / 12, r = slot - sb2 * 12, G = r / 3, s = r - G * 3, u = s * 4 + sb2;
      bls[slot] = (u < HID) ? bias[G * HID + u] * gscale(G) : 0.f;
    }
  }

  // recurrent weights (gate-scaled); plain init, no keep-alive (round-2 lesson)
  float Whr[HID][12];
  #pragma unroll
  for (int j = 0; j < 12; ++j) {
    const int G = j / 3, s = j - G * 3, u = s * 4 + sub;
    #pragma unroll
    for (int k = 0; k < HID; ++k)
      Whr[k][j] = (u < HID) ? Wh[k * GATES + G * HID + u] * gscale(G) : 0.f;
  }

  __syncthreads();

  float h[HID], cst[3];
  #pragma unroll
  for (int k = 0; k < HID; ++k) h[k] = 0.f;
  cst[0] = cst[1] = cst[2] = 0.f;

  const int* xrow = xs + lb * SEQ;

  if constexpr (USEP) {
    int2 pA[3], pB[3], pC[3];
    auto ldrow = [&](int2 (&p)[3], int t) {
      int row = xrow[t < SEQ ? t : SEQ - 1];
      const int2* q = (const int2*)(P + (size_t)row * PROWH + sub * 12);
      p[0] = q[0]; p[1] = q[1]; p[2] = q[2];
    };
    ldrow(pA, 0); ldrow(pB, 1); ldrow(pC, 2);

    auto lstm_step = [&](int2 (&p)[3], int t) {
      float z[12];
      cvt12(p, z);
      ldrow(p, t + 3);     // issue depth-3 prefetch right after regs freed

      #pragma unroll
      for (int k = 0; k < HID; ++k)
        #pragma unroll
        for (int j = 0; j < 12; ++j)
          z[j] = fmaf(h[k], Whr[k][j], z[j]);

      float a[12];
      #pragma unroll
      for (int j = 0; j < 12; ++j) {
        float r = rcp_f(1.f + exp2_f(z[j]));
        a[j] = (j / 3 == 2) ? fmaf(2.f, r, -1.f) : r;
      }

      float hl[3];
      #pragma unroll
      for (int s = 0; s < 3; ++s) {
        cst[s] = fmaf(a[3 + s], cst[s], a[s] * a[6 + s]);       // c = f*c + i*g
        float r = rcp_f(1.f + exp2_f(-2.885390081777927f * cst[s]));
        hl[s] = fmaf(a[9 + s], r + r, -a[9 + s]);               // h = o*(2r-1)
      }

      h[0] = qb<0x00>(hl[0]); h[1] = qb<0x55>(hl[0]); h[2] = qb<0xAA>(hl[0]); h[3] = qb<0xFF>(hl[0]);
      h[4] = qb<0x00>(hl[1]); h[5] = qb<0x55>(hl[1]); h[6] = qb<0xAA>(hl[1]); h[7] = qb<0xFF>(hl[1]);
      h[8] = qb<0x00>(hl[2]); h[9] = qb<0x55>(hl[2]);
    };

    #pragma unroll 1
    for (int t = 0; t < SEQ - 1; t += 3) {   // 33 triples -> t=0..98
      lstm_step(pA, t);
      lstm_step(pB, t + 1);
      lstm_step(pC, t + 2);
    }
    lstm_step(pA, SEQ - 1);                  // t=99
  } else {
    float bb[12];
    #pragma unroll
    for (int j = 0; j < 12; ++j) bb[j] = bls[sub * 12 + j];
    float4 e0, e1, e2, e3, e4;
    {
      int row = xrow[0];
      const float4* q = (const float4*)(emb + (size_t)row * EMB);
      e0 = q[0]; e1 = q[1]; e2 = q[2]; e3 = q[3]; e4 = q[4];
    }
    #pragma unroll 1
    for (int t = 0; t < SEQ; ++t) {
      float e[EMB] = {e0.x,e0.y,e0.z,e0.w, e1.x,e1.y,e1.z,e1.w, e2.x,e2.y,e2.z,e2.w,
                      e3.x,e3.y,e3.z,e3.w, e4.x,e4.y,e4.z,e4.w};
      float z[12];
      #pragma unroll
      for (int j = 0; j < 12; ++j) z[j] = bb[j];
      const int wbase = sub * 12;
      #pragma unroll
      for (int k = 0; k < EMB; ++k)
        #pragma unroll
        for (int j = 0; j < 12; ++j)
          z[j] = fmaf(e[k], Wxl[k * PROWH + wbase + j], z[j]);
      if (t + 1 < SEQ) {
        int row = xrow[t + 1];
        const float4* q = (const float4*)(emb + (size_t)row * EMB);
        e0 = q[0]; e1 = q[1]; e2 = q[2]; e3 = q[3]; e4 = q[4];
      }
      #pragma unroll
      for (int k = 0; k < HID; ++k)
        #pragma unroll
        for (int j = 0; j < 12; ++j)
          z[j] = fmaf(h[k], Whr[k][j], z[j]);
      float a[12];
      #pragma unroll
      for (int j = 0; j < 12; ++j) {
        float r = rcp_f(1.f + exp2_f(z[j]));
        a[j] = (j / 3 == 2) ? fmaf(2.f, r, -1.f) : r;
      }
      float hl[3];
      #pragma unroll
      for (int s = 0; s < 3; ++s) {
        cst[s] = fmaf(a[3 + s], cst[s], a[s] * a[6 + s]);
        float r = rcp_f(1.f + exp2_f(-2.885390081777927f * cst[s]));
        hl[s] = fmaf(a[9 + s], r + r, -a[9 + s]);
      }
      h[0] = qb<0x00>(hl[0]); h[1] = qb<0x55>(hl[0]); h[2] = qb<0xAA>(hl[0]); h[3] = qb<0xFF>(hl[0]);
      h[4] = qb<0x00>(hl[1]); h[5] = qb<0x55>(hl[1]); h[6] = qb<0xAA>(hl[1]); h[7] = qb<0xFF>(hl[1]);
      h[8] = qb<0x00>(hl[2]); h[9] = qb<0x55>(hl[2]);
    }
  }

  // dense head
  #pragma unroll
  for (int s = 0; s < 4; ++s) {
    int j = s * 4 + sub;
    if (j < NLAB) {
      float acc = bd[j];
      #pragma unroll
      for (int k = 0; k < HID; ++k)
        acc = fmaf(h[k], Wd[k * NLAB + j], acc);
      out[(size_t)(b0 + lb) * NLAB + j] = acc;
    }
  }
}

extern "C" void kernel_launch(void* const* d_in, const int* in_sizes, int n_in,
                              void* d_out, int out_size, void* d_ws, size_t ws_size,
                              hipStream_t stream) {
  (void)in_sizes; (void)n_in; (void)out_size;
  const int*   x    = (const int*)  d_in[0];
  const float* emb  = (const float*)d_in[1];
  const float* Wx   = (const float*)d_in[2];
  const float* Wh   = (const float*)d_in[3];
  const float* bias = (const float*)d_in[4];
  const float* Wd   = (const float*)d_in[5];
  const float* bd   = (const float*)d_in[6];
  float* out = (float*)d_out;

  const size_t pbytes = (size_t)VOCAB * PROWH * sizeof(__half);
  if (ws_size >= pbytes) {
    __half* P = (__half*)d_ws;
    hipLaunchKernelGGL(proj_kernel, dim3((VOCAB + 63) / 64), dim3(256), 0, stream,
                       emb, Wx, bias, P);
    hipLaunchKernelGGL((rnn_kernel<true>), dim3(BATCH / 64), dim3(256), 0, stream,
                       x, P, Wh, Wd, bd, out, emb, Wx, bias);
  } else {
    hipLaunchKernelGGL((rnn_kernel<false>), dim3(BATCH / 64), dim3(256), 0, stream,
                       x, (const __half*)nullptr, Wh, Wd, bd, out, emb, Wx, bias);
  }
}

// Round 4
// 57.270 us; speedup vs baseline: 2.0779x; 1.1613x over previous
//
#include <hip/hip_runtime.h>
#include <hip/hip_fp16.h>

#define VOCAB 100000
#define EMB   20
#define HID   10
#define SEQ   100
#define NLAB  15
#define BATCH 16384
#define GATES 40
#define PROWH 48   // P row: 48 halfs = 96 B; lane sub reads halfs [sub*12 .. sub*12+11]

typedef _Float16 half2_t __attribute__((ext_vector_type(2)));

__device__ __forceinline__ float exp2_f(float x){ float r; asm("v_exp_f32 %0, %1" : "=v"(r) : "v"(x)); return r; }
__device__ __forceinline__ float rcp_f(float x){ float r; asm("v_rcp_f32 %0, %1" : "=v"(r) : "v"(x)); return r; }

// Gate scales folded into P/Wh/bias: sigmoid(x)=rcp(1+exp2(-log2e*x)),
// tanh(x)=(1-E)/(1+E) with E=exp2(-2log2e*x). c-gate scale -2log2e, others -log2e.
__device__ __host__ __forceinline__ constexpr float gscale(int G){
  return (G == 2) ? -2.885390081777927f : -1.442695040888963f;
}

template<int CTRL>
__device__ __forceinline__ float qb(float x){
  return __int_as_float(__builtin_amdgcn_mov_dpp(__float_as_int(x), CTRL, 0xF, 0xF, true));
}
template<int CTRL>
__device__ __forceinline__ int qbi(int x){
  return __builtin_amdgcn_mov_dpp(x, CTRL, 0xF, 0xF, true);
}

__device__ __forceinline__ half2_t h2cast(int i){ union{int i; half2_t h;} u; u.i=i; return u.h; }

__device__ __forceinline__ float fdot2(half2_t a, half2_t b, float c){
#if __has_builtin(__builtin_amdgcn_fdot2)
  return __builtin_amdgcn_fdot2(a, b, c, false);
#else
  return fmaf((float)a[1], (float)b[1], fmaf((float)a[0], (float)b[0], c));
#endif
}

// -------- P = fp16( (embed @ Wx + b) * gate_scale ), [VOCAB][4 sub][4 gate][3 slot]
__global__ __launch_bounds__(256)
void proj_kernel(const float* __restrict__ emb, const float* __restrict__ Wx,
                 const float* __restrict__ bias, __half* __restrict__ P)
{
  __shared__ float Wxl[EMB * PROWH];
  __shared__ float bl[PROWH];
  const int tid = threadIdx.x;
  for (int i = tid; i < EMB * PROWH; i += 256) {
    int k = i / PROWH, slot = i - k * PROWH;
    int sb = slot / 12, r = slot - sb * 12, G = r / 3, s = r - G * 3, u = s * 4 + sb;
    Wxl[i] = (u < HID) ? Wx[k * GATES + G * HID + u] * gscale(G) : 0.f;
  }
  if (tid < PROWH) {
    int slot = tid, sb = slot / 12, r = slot - sb * 12, G = r / 3, s = r - G * 3, u = s * 4 + sb;
    bl[slot] = (u < HID) ? bias[G * HID + u] * gscale(G) : 0.f;
  }
  __syncthreads();

  const int v   = blockIdx.x * 64 + (tid >> 2);
  const int sub = tid & 3;
  if (v >= VOCAB) return;

  const float4* er = (const float4*)(emb + (size_t)v * EMB);
  float4 e0 = er[0], e1 = er[1], e2 = er[2], e3 = er[3], e4 = er[4];
  float e[EMB] = {e0.x,e0.y,e0.z,e0.w, e1.x,e1.y,e1.z,e1.w, e2.x,e2.y,e2.z,e2.w,
                  e3.x,e3.y,e3.z,e3.w, e4.x,e4.y,e4.z,e4.w};
  const int wb = sub * 12;
  float acc[12];
  #pragma unroll
  for (int j = 0; j < 12; ++j) acc[j] = bl[wb + j];
  #pragma unroll
  for (int k = 0; k < EMB; ++k)
    #pragma unroll
    for (int j = 0; j < 12; ++j)
      acc[j] = fmaf(e[k], Wxl[k * PROWH + wb + j], acc[j]);

  union { __half h[12]; int2 i2[3]; } u;
  #pragma unroll
  for (int j = 0; j < 12; ++j) u.h[j] = __float2half(acc[j]);
  int2* o = (int2*)(P + (size_t)v * PROWH + wb);
  o[0] = u.i2[0]; o[1] = u.i2[1]; o[2] = u.i2[2];
}

__device__ __forceinline__ void cvt12(const int2 b[3], float z[12]) {
  #pragma unroll
  for (int q = 0; q < 3; ++q) {
    float2 f0 = __half22float2(*(const __half2*)&b[q].x);
    float2 f1 = __half22float2(*(const __half2*)&b[q].y);
    z[q*4+0] = f0.x; z[q*4+1] = f0.y; z[q*4+2] = f1.x; z[q*4+3] = f1.y;
  }
}

// -------- LSTM recurrence + dense head. 4 lanes per batch element.
template<bool USEP>
__global__ __launch_bounds__(256, 1)
void rnn_kernel(const int* __restrict__ x, const __half* __restrict__ P,
                const float* __restrict__ Wh, const float* __restrict__ Wd,
                const float* __restrict__ bd, float* __restrict__ out,
                const float* __restrict__ emb, const float* __restrict__ Wx,
                const float* __restrict__ bias)
{
  __shared__ int   xs[64 * SEQ];
  __shared__ float Wxl[EMB * PROWH];   // !USEP only
  __shared__ float bls[PROWH];         // !USEP only

  const int tid = threadIdx.x;
  const int lb  = tid >> 2;
  const int sub = tid & 3;
  const int b0  = blockIdx.x * 64;

  for (int i = tid; i < 64 * SEQ; i += 256) xs[i] = x[(size_t)b0 * SEQ + i];

  if constexpr (!USEP) {
    for (int i = tid; i < EMB * PROWH; i += 256) {
      int k = i / PROWH, slot = i - k * PROWH;
      int sb2 = slot / 12, r = slot - sb2 * 12, G = r / 3, s = r - G * 3, u = s * 4 + sb2;
      Wxl[i] = (u < HID) ? Wx[k * GATES + G * HID + u] * gscale(G) : 0.f;
    }
    if (tid < PROWH) {
      int slot = tid, sb2 = slot / 12, r = slot - sb2 * 12, G = r / 3, s = r - G * 3, u = s * 4 + sb2;
      bls[slot] = (u < HID) ? bias[G * HID + u] * gscale(G) : 0.f;
    }
  }

  __syncthreads();

  float cst[3];
  cst[0] = cst[1] = cst[2] = 0.f;

  const int* xrow = xs + lb * SEQ;

  if constexpr (USEP) {
    // fp16 recurrent weights, packed for v_dot2_f32_f16: pairs (k, k+4) for p<4, (8,9) for p=4.
    // 60 half2 regs = 60 VGPRs (vs 120 f32 that never fit in round 3's 88 VGPRs).
    half2_t w2[5][12];
    #pragma unroll
    for (int p = 0; p < 5; ++p) {
      const int k0 = (p < 4) ? p : 8;
      const int k1 = (p < 4) ? p + 4 : 9;
      #pragma unroll
      for (int j = 0; j < 12; ++j) {
        const int G = j / 3, s = j - G * 3, u = s * 4 + sub;
        float a = 0.f, b2 = 0.f;
        if (u < HID) {
          a  = Wh[k0 * GATES + G * HID + u] * gscale(G);
          b2 = Wh[k1 * GATES + G * HID + u] * gscale(G);
        }
        w2[p][j][0] = (_Float16)a;
        w2[p][j][1] = (_Float16)b2;
      }
    }

    int hpi[5] = {0, 0, 0, 0, 0};   // packed h pairs, uniform across the quad
    float hf[HID];                   // f32 h for the dense head at the end
    #pragma unroll
    for (int k = 0; k < HID; ++k) hf[k] = 0.f;

    int2 pA[3], pB[3], pC[3];
    auto ldrow = [&](int2 (&p)[3], int t) {
      int row = xrow[t < SEQ ? t : SEQ - 1];
      const int2* q = (const int2*)(P + (size_t)row * PROWH + sub * 12);
      p[0] = q[0]; p[1] = q[1]; p[2] = q[2];
    };
    ldrow(pA, 0); ldrow(pB, 1); ldrow(pC, 2);

    auto lstm_step = [&](int2 (&p)[3], int t) {
      float z[12];
      cvt12(p, z);
      ldrow(p, t + 3);     // depth-3 prefetch

      // z += h @ Wh via packed fp16 dot2 (f32 accumulate)
      #pragma unroll
      for (int pp = 0; pp < 5; ++pp) {
        half2_t hp = h2cast(hpi[pp]);
        #pragma unroll
        for (int j = 0; j < 12; ++j)
          z[j] = fdot2(hp, w2[pp][j], z[j]);
      }

      // merged-rcp activations per owned unit s: u = s*4+sub
      float hl[3];
      #pragma unroll
      for (int s = 0; s < 3; ++s) {
        float Ei = exp2_f(z[s]);
        float Ef = exp2_f(z[s + 3]);
        float Ec = exp2_f(z[s + 6]);
        float Eo = exp2_f(z[s + 9]);
        float f  = rcp_f(1.f + Ef);
        float ig = (1.f - Ec) * rcp_f((1.f + Ei) * (1.f + Ec));   // sigmoid(i)*tanh(c~)
        cst[s] = fmaf(f, cst[s], ig);                              // c = f*c + i*g
        float Et = exp2_f(-2.885390081777927f * cst[s]);
        hl[s] = (1.f - Et) * rcp_f((1.f + Eo) * (1.f + Et));       // o*tanh(c)
      }

      // keep f32 h for the head (lane-local slots only; head gathers via qb later)
      hf[0] = hl[0]; hf[1] = hl[1]; hf[2] = hl[2];

      // pack (h[sub], h[sub+4]) as fp16 pair, broadcast 4 pairs via quad DPP;
      // pair (h8,h9) assembled from lanes 0,1's third slot via perm.
      union { _Float16 h[2]; int i; } u01, u2;
      u01.h[0] = (_Float16)hl[0]; u01.h[1] = (_Float16)hl[1];
      u2.h[0]  = (_Float16)hl[2]; u2.h[1]  = (_Float16)0.f;
      hpi[0] = qbi<0x00>(u01.i);
      hpi[1] = qbi<0x55>(u01.i);
      hpi[2] = qbi<0xAA>(u01.i);
      hpi[3] = qbi<0xFF>(u01.i);
      hpi[4] = (int)__builtin_amdgcn_perm((unsigned)qbi<0x55>(u2.i),
                                          (unsigned)qbi<0x00>(u2.i), 0x05040100u);
    };

    #pragma unroll 1
    for (int t = 0; t < SEQ - 1; t += 3) {   // 33 triples: t=0..98
      lstm_step(pA, t);
      lstm_step(pB, t + 1);
      lstm_step(pC, t + 2);
    }
    lstm_step(pA, SEQ - 1);                  // t=99

    // gather full h vector (f32) for the head: lane sub holds units {sub,4+sub,8+sub}
    float h[HID];
    h[0] = qb<0x00>(hf[0]); h[1] = qb<0x55>(hf[0]); h[2] = qb<0xAA>(hf[0]); h[3] = qb<0xFF>(hf[0]);
    h[4] = qb<0x00>(hf[1]); h[5] = qb<0x55>(hf[1]); h[6] = qb<0xAA>(hf[1]); h[7] = qb<0xFF>(hf[1]);
    h[8] = qb<0x00>(hf[2]); h[9] = qb<0x55>(hf[2]);

    #pragma unroll
    for (int s = 0; s < 4; ++s) {
      int j = s * 4 + sub;
      if (j < NLAB) {
        float acc = bd[j];
        #pragma unroll
        for (int k = 0; k < HID; ++k)
          acc = fmaf(h[k], Wd[k * NLAB + j], acc);
        out[(size_t)(b0 + lb) * NLAB + j] = acc;
      }
    }
  } else {
    // fallback (ws too small): round-3 f32 path
    float Whr[HID][12];
    #pragma unroll
    for (int j = 0; j < 12; ++j) {
      const int G = j / 3, s = j - G * 3, u = s * 4 + sub;
      #pragma unroll
      for (int k = 0; k < HID; ++k)
        Whr[k][j] = (u < HID) ? Wh[k * GATES + G * HID + u] * gscale(G) : 0.f;
    }
    float h[HID];
    #pragma unroll
    for (int k = 0; k < HID; ++k) h[k] = 0.f;
    float bb[12];
    #pragma unroll
    for (int j = 0; j < 12; ++j) bb[j] = bls[sub * 12 + j];
    float4 e0, e1, e2, e3, e4;
    {
      int row = xrow[0];
      const float4* q = (const float4*)(emb + (size_t)row * EMB);
      e0 = q[0]; e1 = q[1]; e2 = q[2]; e3 = q[3]; e4 = q[4];
    }
    #pragma unroll 1
    for (int t = 0; t < SEQ; ++t) {
      float e[EMB] = {e0.x,e0.y,e0.z,e0.w, e1.x,e1.y,e1.z,e1.w, e2.x,e2.y,e2.z,e2.w,
                      e3.x,e3.y,e3.z,e3.w, e4.x,e4.y,e4.z,e4.w};
      float z[12];
      #pragma unroll
      for (int j = 0; j < 12; ++j) z[j] = bb[j];
      const int wbase = sub * 12;
      #pragma unroll
      for (int k = 0; k < EMB; ++k)
        #pragma unroll
        for (int j = 0; j < 12; ++j)
          z[j] = fmaf(e[k], Wxl[k * PROWH + wbase + j], z[j]);
      if (t + 1 < SEQ) {
        int row = xrow[t + 1];
        const float4* q = (const float4*)(emb + (size_t)row * EMB);
        e0 = q[0]; e1 = q[1]; e2 = q[2]; e3 = q[3]; e4 = q[4];
      }
      #pragma unroll
      for (int k = 0; k < HID; ++k)
        #pragma unroll
        for (int j = 0; j < 12; ++j)
          z[j] = fmaf(h[k], Whr[k][j], z[j]);
      float hl[3];
      #pragma unroll
      for (int s = 0; s < 3; ++s) {
        float Ei = exp2_f(z[s]), Ef = exp2_f(z[s+3]), Ec = exp2_f(z[s+6]), Eo = exp2_f(z[s+9]);
        float f  = rcp_f(1.f + Ef);
        float ig = (1.f - Ec) * rcp_f((1.f + Ei) * (1.f + Ec));
        cst[s] = fmaf(f, cst[s], ig);
        float Et = exp2_f(-2.885390081777927f * cst[s]);
        hl[s] = (1.f - Et) * rcp_f((1.f + Eo) * (1.f + Et));
      }
      h[0] = qb<0x00>(hl[0]); h[1] = qb<0x55>(hl[0]); h[2] = qb<0xAA>(hl[0]); h[3] = qb<0xFF>(hl[0]);
      h[4] = qb<0x00>(hl[1]); h[5] = qb<0x55>(hl[1]); h[6] = qb<0xAA>(hl[1]); h[7] = qb<0xFF>(hl[1]);
      h[8] = qb<0x00>(hl[2]); h[9] = qb<0x55>(hl[2]);
    }
    #pragma unroll
    for (int s = 0; s < 4; ++s) {
      int j = s * 4 + sub;
      if (j < NLAB) {
        float acc = bd[j];
        #pragma unroll
        for (int k = 0; k < HID; ++k)
          acc = fmaf(h[k], Wd[k * NLAB + j], acc);
        out[(size_t)(b0 + lb) * NLAB + j] = acc;
      }
    }
  }
}

extern "C" void kernel_launch(void* const* d_in, const int* in_sizes, int n_in,
                              void* d_out, int out_size, void* d_ws, size_t ws_size,
                              hipStream_t stream) {
  (void)in_sizes; (void)n_in; (void)out_size;
  const int*   x    = (const int*)  d_in[0];
  const float* emb  = (const float*)d_in[1];
  const float* Wx   = (const float*)d_in[2];
  const float* Wh   = (const float*)d_in[3];
  const float* bias = (const float*)d_in[4];
  const float* Wd   = (const float*)d_in[5];
  const float* bd   = (const float*)d_in[6];
  float* out = (float*)d_out;

  const size_t pbytes = (size_t)VOCAB * PROWH * sizeof(__half);
  if (ws_size >= pbytes) {
    __half* P = (__half*)d_ws;
    hipLaunchKernelGGL(proj_kernel, dim3((VOCAB + 63) / 64), dim3(256), 0, stream,
                       emb, Wx, bias, P);
    hipLaunchKernelGGL((rnn_kernel<true>), dim3(BATCH / 64), dim3(256), 0, stream,
                       x, P, Wh, Wd, bd, out, emb, Wx, bias);
  } else {
    hipLaunchKernelGGL((rnn_kernel<false>), dim3(BATCH / 64), dim3(256), 0, stream,
                       x, (const __half*)nullptr, Wh, Wd, bd, out, emb, Wx, bias);
  }
}